// Round 1
// baseline (1343.378 us; speedup 1.0000x reference)
//
#include <hip/hip_runtime.h>
#include <math.h>

#define DIM 768
#define SEQ 2048
#define BAT 2
#define NH 12
#define DH 64
#define ROWS (BAT*SEQ)          // 4096
#define NB ((size_t)ROWS*DIM)   // 3145728 elems per activation buffer

// ---------------------------------------------------------------- LayerNorm
__global__ __launch_bounds__(256) void ln_k(const float* __restrict__ x,
                                            const float* __restrict__ w,
                                            const float* __restrict__ b,
                                            float* __restrict__ out)
{
    int row = blockIdx.x;
    int tid = threadIdx.x;
    const float* xr = x + (size_t)row * DIM;
    float v0 = xr[tid], v1 = xr[tid + 256], v2 = xr[tid + 512];
    float s  = v0 + v1 + v2;
    float ss = v0*v0 + v1*v1 + v2*v2;
    #pragma unroll
    for (int off = 32; off > 0; off >>= 1) {
        s  += __shfl_down(s,  off);
        ss += __shfl_down(ss, off);
    }
    __shared__ float ws_[4], wss_[4];
    __shared__ float mu_s, rs_s;
    int lane = tid & 63, wid = tid >> 6;
    if (lane == 0) { ws_[wid] = s; wss_[wid] = ss; }
    __syncthreads();
    if (tid == 0) {
        float S1 = ws_[0] + ws_[1] + ws_[2] + ws_[3];
        float S2 = wss_[0] + wss_[1] + wss_[2] + wss_[3];
        float m = S1 * (1.0f / DIM);
        float var = S2 * (1.0f / DIM) - m * m;
        mu_s = m;
        rs_s = rsqrtf(var + 1e-5f);
    }
    __syncthreads();
    float mu = mu_s, rs = rs_s;
    float* orow = out + (size_t)row * DIM;
    orow[tid]       = (v0 - mu) * rs * w[tid]       + b[tid];
    orow[tid + 256] = (v1 - mu) * rs * w[tid + 256] + b[tid + 256];
    orow[tid + 512] = (v2 - mu) * rs * w[tid + 512] + b[tid + 512];
}

// ---------------------------------------------------------------- GEMM
// C[4096,768] = A[4096,768] @ W[768,768] + bias, with optional:
//  AMODE=1: A gathered from attention layout [H,B,S,Dh]
//  OMODE=1: C scattered to  [H,B,S,Dh] (QKV split-heads)
//  RELU, RES (residual add from `res`, standard [rows,DIM] layout)
template<int AMODE, int OMODE, bool RELU, bool RES>
__global__ __launch_bounds__(256) void gemm_k(const float* __restrict__ A,
                                              const float* __restrict__ W,
                                              const float* __restrict__ bv,
                                              const float* __restrict__ res,
                                              float* __restrict__ out)
{
    __shared__ float As[16 * 68];   // [k][m], padded pitch
    __shared__ float Bs[16 * 68];   // [k][n]
    int tid = threadIdx.x;
    int tx = tid & 15, ty = tid >> 4;
    int colBase = blockIdx.x * 64;
    int rowBase = blockIdx.y * 64;

    float acc[4][4] = {};

    int lr = tid >> 2;          // A-load: row in tile 0..63
    int lk = (tid & 3) * 4;     // A-load: k offset 0,4,8,12
    int lkk = tid >> 4;         // B-load: k row 0..15
    int lc  = (tid & 15) * 4;   // B-load: col offset

    for (int kt = 0; kt < DIM; kt += 16) {
        float4 a4;
        if (AMODE == 0) {
            a4 = *(const float4*)&A[(size_t)(rowBase + lr) * DIM + kt + lk];
        } else {
            int col = kt + lk;
            int h = col >> 6, dh = col & 63;
            int r = rowBase + lr;
            int bb = r >> 11, ss2 = r & 2047;
            a4 = *(const float4*)&A[(((size_t)(h * BAT + bb)) * SEQ + ss2) * DH + dh];
        }
        float4 b4 = *(const float4*)&W[(size_t)(kt + lkk) * DIM + colBase + lc];
        As[(lk + 0) * 68 + lr] = a4.x;
        As[(lk + 1) * 68 + lr] = a4.y;
        As[(lk + 2) * 68 + lr] = a4.z;
        As[(lk + 3) * 68 + lr] = a4.w;
        *(float4*)&Bs[lkk * 68 + lc] = b4;
        __syncthreads();
        #pragma unroll
        for (int kk = 0; kk < 16; kk++) {
            float4 av  = *(float4*)&As[kk * 68 + ty * 4];
            float4 bvv = *(float4*)&Bs[kk * 68 + tx * 4];
            float aa[4] = {av.x, av.y, av.z, av.w};
            float bb2[4] = {bvv.x, bvv.y, bvv.z, bvv.w};
            #pragma unroll
            for (int i = 0; i < 4; i++)
                #pragma unroll
                for (int j = 0; j < 4; j++)
                    acc[i][j] = fmaf(aa[i], bb2[j], acc[i][j]);
        }
        __syncthreads();
    }
    #pragma unroll
    for (int i = 0; i < 4; i++) {
        int r  = rowBase + ty * 4 + i;
        int n0 = colBase + tx * 4;
        float vals[4];
        #pragma unroll
        for (int j = 0; j < 4; j++) {
            float v = acc[i][j] + bv[n0 + j];
            if (RELU) v = fmaxf(v, 0.0f);
            if (RES)  v += res[(size_t)r * DIM + n0 + j];
            vals[j] = v;
        }
        float4 o; o.x = vals[0]; o.y = vals[1]; o.z = vals[2]; o.w = vals[3];
        if (OMODE == 0) {
            *(float4*)&out[(size_t)r * DIM + n0] = o;
        } else {
            int h = n0 >> 6, dh = n0 & 63;
            int bb = r >> 11, ss2 = r & 2047;
            *(float4*)&out[(((size_t)(h * BAT + bb)) * SEQ + ss2) * DH + dh] = o;
        }
    }
}

// ---------------------------------------------------------------- Attention
// Flash-style: per (h,b) and 64-row Q tile, stream 64-row K/V tiles with
// online softmax. logits = (q.kT + bias)/8, masked -> -1.25e18 (== -1e20/8 scale-equiv).
#define AP 68
__global__ __launch_bounds__(256) void attn_k(const float* __restrict__ q,
                                              const float* __restrict__ k,
                                              const float* __restrict__ v,
                                              const float* __restrict__ bias,
                                              const int* __restrict__ mask,
                                              float* __restrict__ out)
{
    __shared__ float Qs[64 * AP];   // [d][r]
    __shared__ float Ks[64 * AP];   // phase 1: K as [d][c]; phase 2: V as [j][cc]
    __shared__ float Pt[64 * AP];   // P transposed: [c][r]
    __shared__ float mrow[64], lrow[64], arow[64];

    int tid = threadIdx.x;
    int tx = tid & 15, ty = tid >> 4;
    int qt = blockIdx.x;             // 0..31
    int hb = blockIdx.y;             // h*B + b
    int bb = hb & (BAT - 1);
    int qbase = qt * 64;

    const float* qp = q + (size_t)hb * SEQ * DH;
    const float* kp = k + (size_t)hb * SEQ * DH;
    const float* vp = v + (size_t)hb * SEQ * DH;
    const float* bp = bias + ((size_t)hb * SEQ + qbase) * SEQ;
    const int*   mp = mask + ((size_t)bb * SEQ + qbase) * SEQ;

    {   // Q tile, transposed store
        int r = tid >> 2;
        int d0 = (tid & 3) * 16;
        const float* src = &qp[(size_t)(qbase + r) * DH + d0];
        #pragma unroll
        for (int t = 0; t < 4; t++) {
            float4 a = *(const float4*)&src[t * 4];
            Qs[(d0 + t*4 + 0) * AP + r] = a.x;
            Qs[(d0 + t*4 + 1) * AP + r] = a.y;
            Qs[(d0 + t*4 + 2) * AP + r] = a.z;
            Qs[(d0 + t*4 + 3) * AP + r] = a.w;
        }
    }
    if (tid < 64) { mrow[tid] = -INFINITY; lrow[tid] = 0.0f; }
    float O[4][4] = {};
    __syncthreads();

    for (int kvb = 0; kvb < SEQ; kvb += 64) {
        {   // K tile, transposed store Ks[d][c]
            int c = tid >> 2;
            int d0 = (tid & 3) * 16;
            const float* src = &kp[(size_t)(kvb + c) * DH + d0];
            #pragma unroll
            for (int t = 0; t < 4; t++) {
                float4 a = *(const float4*)&src[t * 4];
                Ks[(d0 + t*4 + 0) * AP + c] = a.x;
                Ks[(d0 + t*4 + 1) * AP + c] = a.y;
                Ks[(d0 + t*4 + 2) * AP + c] = a.z;
                Ks[(d0 + t*4 + 3) * AP + c] = a.w;
            }
        }
        __syncthreads();
        // S = Q K^T  (4x4 micro-tile per thread)
        float sa[4][4] = {};
        #pragma unroll 8
        for (int d = 0; d < 64; d++) {
            float4 qv = *(float4*)&Qs[d * AP + ty * 4];
            float4 kv = *(float4*)&Ks[d * AP + tx * 4];
            float qa[4] = {qv.x, qv.y, qv.z, qv.w};
            float ka[4] = {kv.x, kv.y, kv.z, kv.w};
            #pragma unroll
            for (int i = 0; i < 4; i++)
                #pragma unroll
                for (int j = 0; j < 4; j++)
                    sa[i][j] = fmaf(qa[i], ka[j], sa[i][j]);
        }
        // bias + mask + scale, store logits transposed Pt[c][r]
        #pragma unroll
        for (int i = 0; i < 4; i++) {
            int row = ty * 4 + i;
            float4 bb4 = *(const float4*)&bp[(size_t)row * SEQ + kvb + tx * 4];
            int4   mm  = *(const int4*)  &mp[(size_t)row * SEQ + kvb + tx * 4];
            float ba[4] = {bb4.x, bb4.y, bb4.z, bb4.w};
            int   ma[4] = {mm.x, mm.y, mm.z, mm.w};
            #pragma unroll
            for (int j = 0; j < 4; j++) {
                float lg = ma[j] ? (sa[i][j] + ba[j]) * 0.125f : -1.25e18f;
                Pt[(tx * 4 + j) * AP + row] = lg;
            }
        }
        __syncthreads();
        {   // V tile into Ks (row-major [j][cc]) — Ks reads all done above
            int j = tid >> 2;
            int c0 = (tid & 3) * 16;
            const float* src = &vp[(size_t)(kvb + j) * DH + c0];
            #pragma unroll
            for (int t = 0; t < 4; t++) {
                float4 a = *(const float4*)&src[t * 4];
                *(float4*)&Ks[j * AP + c0 + t * 4] = a;
            }
        }
        {   // online softmax: 4 threads per row
            int r = tid >> 2, part = tid & 3;
            float tm = -INFINITY;
            #pragma unroll
            for (int jj = 0; jj < 16; jj++)
                tm = fmaxf(tm, Pt[(part * 16 + jj) * AP + r]);
            tm = fmaxf(tm, __shfl_xor(tm, 1));
            tm = fmaxf(tm, __shfl_xor(tm, 2));
            float mold = mrow[r];
            float mnew = fmaxf(mold, tm);
            float ps = 0.0f;
            #pragma unroll
            for (int jj = 0; jj < 16; jj++) {
                int idx = (part * 16 + jj) * AP + r;
                float p = __expf(Pt[idx] - mnew);
                Pt[idx] = p;
                ps += p;
            }
            ps += __shfl_xor(ps, 1);
            ps += __shfl_xor(ps, 2);
            if (part == 0) {
                float al = __expf(mold - mnew);
                arow[r] = al;
                lrow[r] = lrow[r] * al + ps;
                mrow[r] = mnew;
            }
        }
        __syncthreads();
        // O = alpha*O + P V
        float al[4];
        #pragma unroll
        for (int i = 0; i < 4; i++) al[i] = arow[ty * 4 + i];
        #pragma unroll
        for (int i = 0; i < 4; i++)
            #pragma unroll
            for (int j = 0; j < 4; j++)
                O[i][j] *= al[i];
        #pragma unroll 8
        for (int j = 0; j < 64; j++) {
            float4 pv = *(float4*)&Pt[j * AP + ty * 4];
            float4 vv = *(float4*)&Ks[j * AP + tx * 4];
            float pa[4] = {pv.x, pv.y, pv.z, pv.w};
            float va[4] = {vv.x, vv.y, vv.z, vv.w};
            #pragma unroll
            for (int i = 0; i < 4; i++)
                #pragma unroll
                for (int jj = 0; jj < 4; jj++)
                    O[i][jj] = fmaf(pa[i], va[jj], O[i][jj]);
        }
        __syncthreads();
    }
    #pragma unroll
    for (int i = 0; i < 4; i++) {
        int r = ty * 4 + i;
        float inv = 1.0f / lrow[r];
        float4 o;
        o.x = O[i][0] * inv; o.y = O[i][1] * inv;
        o.z = O[i][2] * inv; o.w = O[i][3] * inv;
        *(float4*)&out[((size_t)hb * SEQ + qbase + r) * DH + tx * 4] = o;
    }
}

// ---------------------------------------------------------------- launch
extern "C" void kernel_launch(void* const* d_in, const int* in_sizes, int n_in,
                              void* d_out, int out_size, void* d_ws, size_t ws_size,
                              hipStream_t stream)
{
    const float* x    = (const float*)d_in[0];
    const float* bias = (const float*)d_in[1];
    const int*   mask = (const int*)d_in[2];
    const float* ln1w = (const float*)d_in[3];
    const float* ln1b = (const float*)d_in[4];
    const float* wq   = (const float*)d_in[5];
    const float* bq   = (const float*)d_in[6];
    const float* wk   = (const float*)d_in[7];
    const float* bk   = (const float*)d_in[8];
    const float* wv   = (const float*)d_in[9];
    const float* bv   = (const float*)d_in[10];
    const float* wo   = (const float*)d_in[11];
    const float* bo   = (const float*)d_in[12];
    const float* ln2w = (const float*)d_in[13];
    const float* ln2b = (const float*)d_in[14];
    const float* w1   = (const float*)d_in[15];
    const float* b1   = (const float*)d_in[16];
    const float* w2   = (const float*)d_in[17];
    const float* b2   = (const float*)d_in[18];
    float* out = (float*)d_out;

    float* ws  = (float*)d_ws;
    float* xn  = ws;            // LN1 out; reused as x1 (post-attn residual)
    float* qb  = ws + NB;       // Q [H,B,S,Dh]; reused as xn2
    float* kb  = ws + NB * 2;   // K; reused as FFN hidden
    float* vb  = ws + NB * 3;   // V
    float* atn = ws + NB * 4;   // attention out [H,B,S,Dh]
    float* x1  = xn;
    float* xn2 = qb;
    float* hbf = kb;

    dim3 gg(12, 64), gb(256);
    ln_k<<<4096, 256, 0, stream>>>(x, ln1w, ln1b, xn);
    gemm_k<0,1,false,false><<<gg, gb, 0, stream>>>(xn, wq, bq, nullptr, qb);
    gemm_k<0,1,false,false><<<gg, gb, 0, stream>>>(xn, wk, bk, nullptr, kb);
    gemm_k<0,1,false,false><<<gg, gb, 0, stream>>>(xn, wv, bv, nullptr, vb);
    attn_k<<<dim3(32, 24), 256, 0, stream>>>(qb, kb, vb, bias, mask, atn);
    gemm_k<1,0,false,true><<<gg, gb, 0, stream>>>(atn, wo, bo, x, x1);
    ln_k<<<4096, 256, 0, stream>>>(x1, ln2w, ln2b, xn2);
    gemm_k<0,0,true,false><<<gg, gb, 0, stream>>>(xn2, w1, b1, nullptr, hbf);
    gemm_k<0,0,false,true><<<gg, gb, 0, stream>>>(hbf, w2, b2, x1, out);
}

// Round 2
// 750.474 us; speedup vs baseline: 1.7900x; 1.7900x over previous
//
#include <hip/hip_runtime.h>
#include <math.h>

#define DIMM 768
#define SEQ 2048
#define BATB 2
#define NHEAD 12
#define DHEAD 64
#define ROWS 4096

typedef __attribute__((ext_vector_type(8))) short bf16x8;
typedef __attribute__((ext_vector_type(4))) float f32x4;
typedef unsigned short ushort_t;
typedef unsigned int uint_t;

union U16 { int4 i; ushort_t u[8]; };

__device__ __forceinline__ ushort_t f2b(float f) {
    uint_t u = __float_as_uint(f);
    return (ushort_t)((u + 0x7FFFu + ((u >> 16) & 1u)) >> 16);
}

// ---------------------------------------------------------------- weight transpose fp32[k][n] -> bf16[n][k]
struct WPtrs { const float* s[6]; };

__global__ __launch_bounds__(256) void wtrans_k(WPtrs wp, ushort_t* __restrict__ dst)
{
    __shared__ float T[64][65];
    int wi = blockIdx.z;
    const float* in = wp.s[wi];
    ushort_t* out = dst + (size_t)wi * (DIMM * DIMM);
    int kb = blockIdx.y * 64, nb = blockIdx.x * 64;
    int t = threadIdx.x;
    int kl = t >> 4, nl = (t & 15) * 4;
    #pragma unroll
    for (int it = 0; it < 4; it++) {
        float4 a = *(const float4*)&in[(size_t)(kb + kl + it * 16) * DIMM + nb + nl];
        T[kl + it * 16][nl + 0] = a.x;
        T[kl + it * 16][nl + 1] = a.y;
        T[kl + it * 16][nl + 2] = a.z;
        T[kl + it * 16][nl + 3] = a.w;
    }
    __syncthreads();
    int no = t >> 2, ko = (t & 3) * 16;
    #pragma unroll
    for (int j = 0; j < 2; j++) {
        U16 u;
        #pragma unroll
        for (int c = 0; c < 8; c++) u.u[c] = f2b(T[ko + j * 8 + c][no]);
        *(int4*)&out[(size_t)(nb + no) * DIMM + kb + ko + j * 8] = u.i;
    }
}

// ---------------------------------------------------------------- LayerNorm (fp32 in -> bf16 out)
__global__ __launch_bounds__(256) void ln_k(const float* __restrict__ x,
                                            const float* __restrict__ w,
                                            const float* __restrict__ b,
                                            ushort_t* __restrict__ out)
{
    int row = blockIdx.x;
    int tid = threadIdx.x;
    const float* xr = x + (size_t)row * DIMM;
    float v0 = xr[tid], v1 = xr[tid + 256], v2 = xr[tid + 512];
    float s  = v0 + v1 + v2;
    float ss = v0 * v0 + v1 * v1 + v2 * v2;
    #pragma unroll
    for (int off = 32; off > 0; off >>= 1) {
        s  += __shfl_down(s,  off);
        ss += __shfl_down(ss, off);
    }
    __shared__ float ws_[4], wss_[4];
    __shared__ float mu_s, rs_s;
    int lane = tid & 63, wid = tid >> 6;
    if (lane == 0) { ws_[wid] = s; wss_[wid] = ss; }
    __syncthreads();
    if (tid == 0) {
        float S1 = ws_[0] + ws_[1] + ws_[2] + ws_[3];
        float S2 = wss_[0] + wss_[1] + wss_[2] + wss_[3];
        float m = S1 * (1.0f / DIMM);
        float var = S2 * (1.0f / DIMM) - m * m;
        mu_s = m;
        rs_s = rsqrtf(var + 1e-5f);
    }
    __syncthreads();
    float mu = mu_s, rs = rs_s;
    ushort_t* orow = out + (size_t)row * DIMM;
    orow[tid]       = f2b((v0 - mu) * rs * w[tid]       + b[tid]);
    orow[tid + 256] = f2b((v1 - mu) * rs * w[tid + 256] + b[tid + 256]);
    orow[tid + 512] = f2b((v2 - mu) * rs * w[tid + 512] + b[tid + 512]);
}

// ---------------------------------------------------------------- MFMA GEMM
// C[4096,768] = A[4096,768] @ W[768,768] + bias
// ASRC: 1 = bf16 row-major, 2 = bf16 gathered from [h,b,s,dh]
// OMODE: 0 = fp32 row-major, 1 = bf16 row-major, 2 = bf16 scatter to [h,b,s,dh]
// LDS is fragment-ordered: slot*64*16B + lane*16B -> ds_read_b128 conflict-free.
template<int ASRC, int OMODE, bool RELU, bool RES>
__global__ __launch_bounds__(256) void mgemm_k(const ushort_t* __restrict__ A,
                                               const ushort_t* __restrict__ BT,
                                               const float* __restrict__ bias,
                                               const float* __restrict__ res,
                                               void* __restrict__ outv)
{
    __shared__ alignas(16) ushort_t Asl[8 * 64 * 8];
    __shared__ alignas(16) ushort_t Bsl[8 * 64 * 8];
    int tid = threadIdx.x;
    int lane = tid & 63, w = tid >> 6;
    int colBase = blockIdx.x * 64, rowBase = blockIdx.y * 64;

    f32x4 acc[4];
    #pragma unroll
    for (int nt = 0; nt < 4; nt++) { f32x4 z = {0.f, 0.f, 0.f, 0.f}; acc[nt] = z; }

    int sm = tid >> 2;            // 0..63: A-row / BT-row within tile
    int sko = (tid & 3) * 16;     // k offset group

    for (int kt = 0; kt < DIMM; kt += 64) {
        // ---- stage A (bf16 16B chunks -> fragment order)
        #pragma unroll
        for (int j = 0; j < 2; j++) {
            int k = sko + j * 8;
            size_t gidx;
            if (ASRC == 1) {
                gidx = (size_t)(rowBase + sm) * DIMM + kt + k;
            } else {
                int r = rowBase + sm, kg = kt + k;
                gidx = ((size_t)((kg >> 6) * BATB + (r >> 11)) * SEQ + (r & 2047)) * DHEAD + (kg & 63);
            }
            int4 a = *(const int4*)&A[gidx];
            int ln = (sm & 15) | (((k & 31) >> 3) << 4);
            int slot = ((sm >> 4) << 1) | (k >> 5);
            *(int4*)&Asl[(slot * 64 + ln) * 8] = a;
        }
        // ---- stage B (bf16 W^T row-major -> fragment order)
        #pragma unroll
        for (int j = 0; j < 2; j++) {
            int k = sko + j * 8;
            int4 b = *(const int4*)&BT[(size_t)(colBase + sm) * DIMM + kt + k];
            int ln = (sm & 15) | (((k & 31) >> 3) << 4);
            int slot = (k >> 5) * 4 + (sm >> 4);
            *(int4*)&Bsl[(slot * 64 + ln) * 8] = b;
        }
        __syncthreads();
        bf16x8 a0 = *(bf16x8*)&Asl[((w * 2 + 0) * 64 + lane) * 8];
        bf16x8 a1 = *(bf16x8*)&Asl[((w * 2 + 1) * 64 + lane) * 8];
        #pragma unroll
        for (int nt = 0; nt < 4; nt++) {
            bf16x8 b0 = *(bf16x8*)&Bsl[((0 * 4 + nt) * 64 + lane) * 8];
            bf16x8 b1 = *(bf16x8*)&Bsl[((1 * 4 + nt) * 64 + lane) * 8];
            acc[nt] = __builtin_amdgcn_mfma_f32_16x16x32_bf16(a0, b0, acc[nt], 0, 0, 0);
            acc[nt] = __builtin_amdgcn_mfma_f32_16x16x32_bf16(a1, b1, acc[nt], 0, 0, 0);
        }
        __syncthreads();
    }
    // ---- epilogue (C layout: col = lane&15 within 16-tile, row = quad*4+reg)
    int col_l = lane & 15, quad = lane >> 4;
    #pragma unroll
    for (int nt = 0; nt < 4; nt++) {
        int n = colBase + nt * 16 + col_l;
        float bn = bias[n];
        #pragma unroll
        for (int r = 0; r < 4; r++) {
            int row = rowBase + w * 16 + quad * 4 + r;
            float v = acc[nt][r] + bn;
            if (RELU) v = fmaxf(v, 0.0f);
            if (RES)  v += res[(size_t)row * DIMM + n];
            if (OMODE == 0) {
                ((float*)outv)[(size_t)row * DIMM + n] = v;
            } else if (OMODE == 1) {
                ((ushort_t*)outv)[(size_t)row * DIMM + n] = f2b(v);
            } else {
                ((ushort_t*)outv)[((size_t)((n >> 6) * BATB + (row >> 11)) * SEQ + (row & 2047)) * DHEAD + (n & 63)] = f2b(v);
            }
        }
    }
}

// ---------------------------------------------------------------- MFMA flash attention
// q,k,v bf16 [hb][s][64]; bias fp32 [hb][s][s]; mask int [b][s][s]; out bf16 [hb][s][64]
__global__ __launch_bounds__(256) void attn_k(const ushort_t* __restrict__ q,
                                              const ushort_t* __restrict__ k,
                                              const ushort_t* __restrict__ v,
                                              const float* __restrict__ bias,
                                              const int* __restrict__ mask,
                                              ushort_t* __restrict__ out)
{
    __shared__ alignas(16) ushort_t Kf[8 * 64 * 8];
    __shared__ alignas(16) ushort_t Vf[8 * 64 * 8];
    __shared__ alignas(16) ushort_t Pf[8 * 64 * 8];
    int tid = threadIdx.x, lane = tid & 63, w = tid >> 6;
    int col_l = lane & 15, quad = lane >> 4;
    int qbase = blockIdx.x * 64;
    int hb = blockIdx.y;
    const ushort_t* qp = q + (size_t)hb * SEQ * DHEAD;
    const ushort_t* kp = k + (size_t)hb * SEQ * DHEAD;
    const ushort_t* vp = v + (size_t)hb * SEQ * DHEAD;
    const float* bp = bias + (size_t)hb * SEQ * SEQ;
    const int*   mp = mask + (size_t)(hb & 1) * SEQ * SEQ;

    // Q A-fragments (lane holds Q[m=lane&15][(lane>>4)*8 + i]), 2 k-halves
    bf16x8 qF0 = *(const bf16x8*)&qp[(size_t)(qbase + w * 16 + col_l) * DHEAD + (quad * 8)];
    bf16x8 qF1 = *(const bf16x8*)&qp[(size_t)(qbase + w * 16 + col_l) * DHEAD + 32 + (quad * 8)];

    f32x4 O[4];
    #pragma unroll
    for (int nt = 0; nt < 4; nt++) { f32x4 z = {0.f, 0.f, 0.f, 0.f}; O[nt] = z; }
    float m_run[4], l_run[4];
    #pragma unroll
    for (int r = 0; r < 4; r++) { m_run[r] = -1e30f; l_run[r] = 0.0f; }

    int sn = tid >> 2, sko = (tid & 3) * 16;   // K staging
    int j0 = (tid >> 3) * 2, e0 = (tid & 7) * 8; // V staging (row pair)

    for (int kvb = 0; kvb < SEQ; kvb += 64) {
        // ---- stage K tile, fragment order (straight 16B copies)
        #pragma unroll
        for (int jj = 0; jj < 2; jj++) {
            int kk = sko + jj * 8;
            int4 kd = *(const int4*)&kp[(size_t)(kvb + sn) * DHEAD + kk];
            int slot = (kk >> 5) * 4 + (sn >> 4);
            int ln = (sn & 15) | (((kk & 31) >> 3) << 4);
            *(int4*)&Kf[(slot * 64 + ln) * 8] = kd;
        }
        // ---- stage V tile transposed into fragment order (paired rows -> b32 writes)
        {
            U16 g0, g1;
            g0.i = *(const int4*)&vp[(size_t)(kvb + j0) * DHEAD + e0];
            g1.i = *(const int4*)&vp[(size_t)(kvb + j0 + 1) * DHEAD + e0];
            int js = j0 >> 5, grp = (j0 & 31) >> 3, i0 = j0 & 7;
            #pragma unroll
            for (int c = 0; c < 8; c++) {
                int n = e0 + c;
                uint_t pk = (uint_t)g0.u[c] | ((uint_t)g1.u[c] << 16);
                int idx = ((js * 4 + (n >> 4)) * 64 + ((n & 15) | (grp << 4))) * 8 + i0;
                *(uint_t*)&Vf[idx] = pk;
            }
        }
        // ---- bias + mask loads (issued early; overlap staging+MFMA latency)
        float bl[4][4]; int ml[4][4];
        #pragma unroll
        for (int nt = 0; nt < 4; nt++) {
            int col = kvb + nt * 16 + col_l;
            #pragma unroll
            for (int r = 0; r < 4; r++) {
                int qrow = qbase + w * 16 + quad * 4 + r;
                bl[nt][r] = bp[(size_t)qrow * SEQ + col];
                ml[nt][r] = mp[(size_t)qrow * SEQ + col];
            }
        }
        __syncthreads();
        // ---- S = Q K^T
        f32x4 S[4];
        #pragma unroll
        for (int nt = 0; nt < 4; nt++) {
            bf16x8 b0 = *(bf16x8*)&Kf[((0 * 4 + nt) * 64 + lane) * 8];
            bf16x8 b1 = *(bf16x8*)&Kf[((1 * 4 + nt) * 64 + lane) * 8];
            f32x4 z = {0.f, 0.f, 0.f, 0.f};
            z = __builtin_amdgcn_mfma_f32_16x16x32_bf16(qF0, b0, z, 0, 0, 0);
            S[nt] = __builtin_amdgcn_mfma_f32_16x16x32_bf16(qF1, b1, z, 0, 0, 0);
        }
        // ---- logits
        float lg[4][4];
        #pragma unroll
        for (int nt = 0; nt < 4; nt++)
            #pragma unroll
            for (int r = 0; r < 4; r++)
                lg[nt][r] = ml[nt][r] ? (S[nt][r] + bl[nt][r]) * 0.125f : -1.25e19f;
        // ---- online softmax (rows live in 16-lane quads)
        float alpha[4];
        #pragma unroll
        for (int r = 0; r < 4; r++) {
            float mx = fmaxf(fmaxf(lg[0][r], lg[1][r]), fmaxf(lg[2][r], lg[3][r]));
            mx = fmaxf(mx, __shfl_xor(mx, 1));
            mx = fmaxf(mx, __shfl_xor(mx, 2));
            mx = fmaxf(mx, __shfl_xor(mx, 4));
            mx = fmaxf(mx, __shfl_xor(mx, 8));
            float mnew = fmaxf(m_run[r], mx);
            alpha[r] = __expf(m_run[r] - mnew);
            m_run[r] = mnew;
            float rs = 0.0f;
            #pragma unroll
            for (int nt = 0; nt < 4; nt++) {
                float p = __expf(lg[nt][r] - mnew);
                lg[nt][r] = p;
                rs += p;
            }
            rs += __shfl_xor(rs, 1);
            rs += __shfl_xor(rs, 2);
            rs += __shfl_xor(rs, 4);
            rs += __shfl_xor(rs, 8);
            l_run[r] = l_run[r] * alpha[r] + rs;
        }
        #pragma unroll
        for (int nt = 0; nt < 4; nt++)
            #pragma unroll
            for (int r = 0; r < 4; r++)
                O[nt][r] *= alpha[r];
        // ---- P (C-layout) -> bf16 -> Pf (A-fragment order, wave-private)
        #pragma unroll
        for (int nt = 0; nt < 4; nt++) {
            int j = nt * 16 + col_l;
            #pragma unroll
            for (int r = 0; r < 4; r++) {
                ushort_t pu = f2b(lg[nt][r]);
                uint_t po = (uint_t)(unsigned)__shfl_xor((int)pu, 1);
                if ((lane & 1) == 0) {
                    int m = quad * 4 + r;
                    int idx = ((w * 2 + (j >> 5)) * 64 + (m | (((j & 31) >> 3) << 4))) * 8 + (j & 7);
                    *(uint_t*)&Pf[idx] = (uint_t)pu | (po << 16);
                }
            }
        }
        // ---- O += P V
        #pragma unroll
        for (int js = 0; js < 2; js++) {
            bf16x8 pF = *(bf16x8*)&Pf[((w * 2 + js) * 64 + lane) * 8];
            #pragma unroll
            for (int nt = 0; nt < 4; nt++) {
                bf16x8 vF = *(bf16x8*)&Vf[((js * 4 + nt) * 64 + lane) * 8];
                O[nt] = __builtin_amdgcn_mfma_f32_16x16x32_bf16(pF, vF, O[nt], 0, 0, 0);
            }
        }
        __syncthreads();
    }
    // ---- write out bf16 [hb][s][dh]
    float inv[4];
    #pragma unroll
    for (int r = 0; r < 4; r++) inv[r] = 1.0f / l_run[r];
    #pragma unroll
    for (int nt = 0; nt < 4; nt++)
        #pragma unroll
        for (int r = 0; r < 4; r++) {
            int row = qbase + w * 16 + quad * 4 + r;
            out[((size_t)hb * SEQ + row) * DHEAD + nt * 16 + col_l] = f2b(O[nt][r] * inv[r]);
        }
}

// ---------------------------------------------------------------- launch
extern "C" void kernel_launch(void* const* d_in, const int* in_sizes, int n_in,
                              void* d_out, int out_size, void* d_ws, size_t ws_size,
                              hipStream_t stream)
{
    const float* x    = (const float*)d_in[0];
    const float* bias = (const float*)d_in[1];
    const int*   mask = (const int*)d_in[2];
    const float* ln1w = (const float*)d_in[3];
    const float* ln1b = (const float*)d_in[4];
    const float* wq   = (const float*)d_in[5];
    const float* bq   = (const float*)d_in[6];
    const float* wk   = (const float*)d_in[7];
    const float* bk   = (const float*)d_in[8];
    const float* wv   = (const float*)d_in[9];
    const float* bv   = (const float*)d_in[10];
    const float* wo   = (const float*)d_in[11];
    const float* bo   = (const float*)d_in[12];
    const float* ln2w = (const float*)d_in[13];
    const float* ln2b = (const float*)d_in[14];
    const float* w1   = (const float*)d_in[15];
    const float* b1   = (const float*)d_in[16];
    const float* w2   = (const float*)d_in[17];
    const float* b2   = (const float*)d_in[18];

    const size_t WSZ = (size_t)DIMM * DIMM;        // 589824
    const size_t ABUF = (size_t)ROWS * DIMM;       // 3145728

    ushort_t* wsu  = (ushort_t*)d_ws;
    ushort_t* wT   = wsu;                          // 6 transposed bf16 weights
    ushort_t* qb   = wsu + 6 * WSZ;
    ushort_t* kbuf = qb + ABUF;
    ushort_t* vbuf = kbuf + ABUF;
    ushort_t* xn1  = vbuf + ABUF;                  // LN1 out; reused: attnout, LN2 out
    float*    x1   = (float*)(xn1 + ABUF);         // fp32 post-attn residual
    ushort_t* hid  = qb;                           // FFN hidden reuses q

    WPtrs wp; wp.s[0] = wq; wp.s[1] = wk; wp.s[2] = wv; wp.s[3] = wo; wp.s[4] = w1; wp.s[5] = w2;

    dim3 gg(12, 64), gb(256);
    wtrans_k<<<dim3(12, 12, 6), 256, 0, stream>>>(wp, wT);
    ln_k<<<ROWS, 256, 0, stream>>>(x, ln1w, ln1b, xn1);
    mgemm_k<1, 2, false, false><<<gg, gb, 0, stream>>>(xn1, wT + 0 * WSZ, bq, nullptr, qb);
    mgemm_k<1, 2, false, false><<<gg, gb, 0, stream>>>(xn1, wT + 1 * WSZ, bk, nullptr, kbuf);
    mgemm_k<1, 2, false, false><<<gg, gb, 0, stream>>>(xn1, wT + 2 * WSZ, bv, nullptr, vbuf);
    attn_k<<<dim3(32, 24), 256, 0, stream>>>(qb, kbuf, vbuf, bias, mask, xn1);
    mgemm_k<2, 0, false, true><<<gg, gb, 0, stream>>>(xn1, wT + 3 * WSZ, bo, x, x1);
    ln_k<<<ROWS, 256, 0, stream>>>(x1, ln2w, ln2b, xn1);
    mgemm_k<1, 1, true, false><<<gg, gb, 0, stream>>>(xn1, wT + 4 * WSZ, b1, nullptr, hid);
    mgemm_k<1, 0, false, true><<<gg, gb, 0, stream>>>(hid, wT + 5 * WSZ, b2, x1, (float*)d_out);
}